// Round 8
// baseline (344.107 us; speedup 1.0000x reference)
//
#include <hip/hip_runtime.h>
#include <math.h>

typedef unsigned short u16;
typedef unsigned int u32;
typedef unsigned short us4 __attribute__((ext_vector_type(4)));
typedef unsigned short us8 __attribute__((ext_vector_type(8)));
typedef short bh8 __attribute__((ext_vector_type(8)));   // 8 bf16 (guide §3)
typedef float f4 __attribute__((ext_vector_type(4)));

#define MFMA16(a, b, c) __builtin_amdgcn_mfma_f32_16x16x32_bf16((a), (b), (c), 0, 0, 0)

__device__ __forceinline__ u16 f2bf(float f) {
  unsigned u = __builtin_bit_cast(unsigned, f);
  u += 0x7FFFu + ((u >> 16) & 1u);   // RNE
  return (u16)(u >> 16);
}
__device__ __forceinline__ float bf2f(u16 h) {
  return __builtin_bit_cast(float, ((unsigned)h) << 16);
}
// gfx950 packed f32->bf16 RNE convert (T12 recipe: no builtin, inline asm)
__device__ __forceinline__ u32 cvt_pk_bf16(float lo, float hi) {
  u32 r;
  asm("v_cvt_pk_bf16_f32 %0, %1, %2" : "=v"(r) : "v"(lo), "v"(hi));
  return r;
}
__device__ __forceinline__ bh8 ld8(const u16* p) {
  return __builtin_bit_cast(bh8, *(const us8*)p);
}
// async global->LDS, 16B per lane. LDS dest = wave-uniform base + lane*16.
__device__ __forceinline__ void gl_lds16(const u16* g, u16* l) {
  __builtin_amdgcn_global_load_lds(
      (const __attribute__((address_space(1))) u32*)g,
      (__attribute__((address_space(3))) u32*)l, 16, 0, 0);
}

// ---------------- fused fp32 -> bf16 (x, Wq, Wkv, Wo) ----------------
__global__ __launch_bounds__(256) void conv4_kernel(const float* __restrict__ x,
                                                    const float* __restrict__ wq,
                                                    const float* __restrict__ wkv,
                                                    const float* __restrict__ wo,
                                                    u16* __restrict__ xb,
                                                    u16* __restrict__ wqb,
                                                    u16* __restrict__ wkvb,
                                                    u16* __restrict__ wob) {
  int i = blockIdx.x * 256 + threadIdx.x;
  const float* in;
  u16* out;
  int j;
  if (i < 2097152) { in = x; out = xb; j = i; }
  else if (i < 3145728) { in = wq; out = wqb; j = i - 2097152; }
  else if (i < 3670016) { in = wkv; out = wkvb; j = i - 3145728; }
  else { in = wo; out = wob; j = i - 3670016; }
  float4 v = ((const float4*)in)[j];
  us4 o;
  o[0] = f2bf(v.x); o[1] = f2bf(v.y); o[2] = f2bf(v.z); o[3] = f2bf(v.w);
  *(us4*)(out + (size_t)j * 4) = o;
}

// ---------------- 256x256 8-wave phase-interleaved QKV GEMM (R16) --------
// T3/T4 port of the 256-sq 8-phase template onto the verified fragment
// formulas. 512 thr = 8 waves (2M x 4N), per-wave 128x64 out, BK=64,
// LDS 128 KB dbuf. Per K-tile: 4 phases, each = {12 ds_read_b128 (one
// C-quadrant) || 2 gl_lds16 (1/4 of tile t+1) -> barrier -> lgkmcnt(0)
// (+sched_barrier, rule #18) -> setprio(1) 16 MFMA setprio(0) -> barrier}.
// Iter-top vmcnt(0)+barrier: all reads of a buffer retire behind a barrier
// before any wave re-stages it (race-free by construction). acc[8][4]=128
// regs + ~80 live ~= 210 < 256-reg cap of an 8-wave block -> no spill.
__global__ __launch_bounds__(512) void gemm_qkv(const u16* __restrict__ A,
                                                const u16* __restrict__ W,
                                                const float* __restrict__ bq,
                                                const float* __restrict__ bkv,
                                                u16* __restrict__ qout,
                                                u16* __restrict__ kvout) {
  const int K = 2048;
  __shared__ __align__(16) u16 lA[2][256][64];
  __shared__ __align__(16) u16 lB[2][256][64];
  const int tid = threadIdx.x;
  const int w = tid >> 6, l = tid & 63, lr = l & 15, lq = l >> 4;
  const int wm = w >> 2, wn = w & 3;               // 2M x 4N wave grid
  const int rowBase = blockIdx.y * 256, colBase = blockIdx.x * 256;
  const int srow = l >> 3;                          // 0..7 in wave's 8-row slab
  const int scol = ((l & 7) ^ srow) * 8;            // swizzled source col

  f4 acc[8][4];
#pragma unroll
  for (int i = 0; i < 8; i++)
#pragma unroll
    for (int j = 0; j < 4; j++) acc[i][j] = (f4)0.0f;

  // stage quarter h (rows h*64..h*64+63) of tile at k0 into buf
  auto STAGE = [&](int buf, int k0, int h) {
    int r = h * 64 + w * 8;                         // wave-uniform row base
    gl_lds16(A + (size_t)(rowBase + r + srow) * K + k0 + scol, &lA[buf][r][0]);
    gl_lds16(W + (size_t)(colBase + r + srow) * K + k0 + scol, &lB[buf][r][0]);
  };

#pragma unroll
  for (int h = 0; h < 4; h++) STAGE(0, 0, h);       // prologue: tile 0

  const int NT = K >> 6;                            // 32
  for (int t = 0; t < NT; t++) {
    const int cur = t & 1, nxt = cur ^ 1;
    asm volatile("s_waitcnt vmcnt(0)" ::: "memory");
    __builtin_amdgcn_sched_barrier(0);
    __builtin_amdgcn_s_barrier();                   // tile t fully in LDS
#pragma unroll
    for (int p = 0; p < 4; p++) {
      const int qm = p & 1, qn = p >> 1;            // C-quadrant
      bh8 af[4][2], bf[2][2];
#pragma unroll
      for (int kx = 0; kx < 2; kx++) {
        int c = ((kx * 4 + lq) ^ (lr & 7)) * 8;
#pragma unroll
        for (int mt = 0; mt < 4; mt++)
          af[mt][kx] = ld8(&lA[cur][wm * 128 + qm * 64 + mt * 16 + lr][c]);
#pragma unroll
        for (int nt = 0; nt < 2; nt++)
          bf[nt][kx] = ld8(&lB[cur][wn * 64 + qn * 32 + nt * 16 + lr][c]);
      }
      if (t + 1 < NT) STAGE(nxt, (t + 1) * 64, p);  // prefetch 1/4 of t+1
      __builtin_amdgcn_sched_barrier(0);
      __builtin_amdgcn_s_barrier();
      asm volatile("s_waitcnt lgkmcnt(0)" ::: "memory");
      __builtin_amdgcn_sched_barrier(0);            // rule #18
      __builtin_amdgcn_s_setprio(1);
#pragma unroll
      for (int kx = 0; kx < 2; kx++)
#pragma unroll
        for (int mt = 0; mt < 4; mt++)
#pragma unroll
          for (int nt = 0; nt < 2; nt++)
            acc[qm * 4 + mt][qn * 2 + nt] =
                MFMA16(af[mt][kx], bf[nt][kx], acc[qm * 4 + mt][qn * 2 + nt]);
      __builtin_amdgcn_s_setprio(0);
      __builtin_amdgcn_s_barrier();
    }
  }

#pragma unroll
  for (int mt = 0; mt < 8; mt++) {
#pragma unroll
    for (int nt = 0; nt < 4; nt++) {
      int col = colBase + wn * 64 + nt * 16 + lr;
      float bv = (col < 2048) ? bq[col] : bkv[col - 2048];
#pragma unroll
      for (int r = 0; r < 4; r++) {
        int row = rowBase + wm * 128 + mt * 16 + 4 * lq + r;
        float v = acc[mt][nt][r] + bv;
        if (col < 2048)
          qout[(size_t)row * 2048 + col] = f2bf(v);
        else
          kvout[(size_t)row * 1024 + col - 2048] = f2bf(v);
      }
    }
  }
}

// ---------------- O projection, same R16 structure (fp32 out) -------------
__global__ __launch_bounds__(512) void gemm_bt(const u16* __restrict__ A,
                                               const u16* __restrict__ W,
                                               float* __restrict__ outp,
                                               int M, int N, int K) {
  __shared__ __align__(16) u16 lA[2][256][64];
  __shared__ __align__(16) u16 lB[2][256][64];
  const int tid = threadIdx.x;
  const int w = tid >> 6, l = tid & 63, lr = l & 15, lq = l >> 4;
  const int wm = w >> 2, wn = w & 3;
  const int rowBase = blockIdx.y * 256, colBase = blockIdx.x * 256;
  const int srow = l >> 3;
  const int scol = ((l & 7) ^ srow) * 8;

  f4 acc[8][4];
#pragma unroll
  for (int i = 0; i < 8; i++)
#pragma unroll
    for (int j = 0; j < 4; j++) acc[i][j] = (f4)0.0f;

  auto STAGE = [&](int buf, int k0, int h) {
    int r = h * 64 + w * 8;
    gl_lds16(A + (size_t)(rowBase + r + srow) * K + k0 + scol, &lA[buf][r][0]);
    gl_lds16(W + (size_t)(colBase + r + srow) * K + k0 + scol, &lB[buf][r][0]);
  };

#pragma unroll
  for (int h = 0; h < 4; h++) STAGE(0, 0, h);

  const int NT = K >> 6;
  for (int t = 0; t < NT; t++) {
    const int cur = t & 1, nxt = cur ^ 1;
    asm volatile("s_waitcnt vmcnt(0)" ::: "memory");
    __builtin_amdgcn_sched_barrier(0);
    __builtin_amdgcn_s_barrier();
#pragma unroll
    for (int p = 0; p < 4; p++) {
      const int qm = p & 1, qn = p >> 1;
      bh8 af[4][2], bf[2][2];
#pragma unroll
      for (int kx = 0; kx < 2; kx++) {
        int c = ((kx * 4 + lq) ^ (lr & 7)) * 8;
#pragma unroll
        for (int mt = 0; mt < 4; mt++)
          af[mt][kx] = ld8(&lA[cur][wm * 128 + qm * 64 + mt * 16 + lr][c]);
#pragma unroll
        for (int nt = 0; nt < 2; nt++)
          bf[nt][kx] = ld8(&lB[cur][wn * 64 + qn * 32 + nt * 16 + lr][c]);
      }
      if (t + 1 < NT) STAGE(nxt, (t + 1) * 64, p);
      __builtin_amdgcn_sched_barrier(0);
      __builtin_amdgcn_s_barrier();
      asm volatile("s_waitcnt lgkmcnt(0)" ::: "memory");
      __builtin_amdgcn_sched_barrier(0);
      __builtin_amdgcn_s_setprio(1);
#pragma unroll
      for (int kx = 0; kx < 2; kx++)
#pragma unroll
        for (int mt = 0; mt < 4; mt++)
#pragma unroll
          for (int nt = 0; nt < 2; nt++)
            acc[qm * 4 + mt][qn * 2 + nt] =
                MFMA16(af[mt][kx], bf[nt][kx], acc[qm * 4 + mt][qn * 2 + nt]);
      __builtin_amdgcn_s_setprio(0);
      __builtin_amdgcn_s_barrier();
    }
  }

#pragma unroll
  for (int mt = 0; mt < 8; mt++) {
#pragma unroll
    for (int nt = 0; nt < 4; nt++) {
      int col = colBase + wn * 64 + nt * 16 + lr;
#pragma unroll
      for (int r = 0; r < 4; r++) {
        int row = rowBase + wm * 128 + mt * 16 + 4 * lq + r;
        outp[(size_t)row * N + col] = acc[mt][nt][r];
      }
    }
  }
}

// ---------------- RoPE in-place on bf16 q and k (R5-exact) ----------------
// Q scaled by 1/sqrt(128) * log2(e): softmax then uses raw exp2.
__global__ __launch_bounds__(256) void rope_kernel(u16* __restrict__ qb,
                                                   u16* __restrict__ kvb) {
  const int NQ = 2 * 2048 * 16 * 64;
  int idx = blockIdx.x * 256 + threadIdx.x;
  u16 *p0, *p1;
  int i, s;
  float sc;
  if (idx < NQ) {
    i = idx & 63;
    int h = (idx >> 6) & 15;
    s = (idx >> 10) & 2047;
    int b = idx >> 21;
    size_t base = (((size_t)(b * 2048 + s)) * 16 + h) * 128;
    p0 = qb + base + i;
    p1 = qb + base + 64 + i;
    sc = 0.12751879522655792f;  // 128^-0.5 * log2(e)
  } else {
    int j = idx - NQ;
    i = j & 63;
    int kh = (j >> 6) & 3;
    s = (j >> 8) & 2047;
    int b = j >> 19;
    size_t base = ((size_t)(b * 2048 + s)) * 1024 + kh * 128;
    p0 = kvb + base + i;
    p1 = kvb + base + 64 + i;
    sc = 1.0f;
  }
  float invf = exp2f(-(float)i * 0.20762050593046012f);
  float ang = (float)s * invf;
  float sn, cs;
  sincosf(ang, &sn, &cs);
  float a1 = bf2f(*p0), a2 = bf2f(*p1);
  *p0 = f2bf((a1 * cs - a2 * sn) * sc);
  *p1 = f2bf((a2 * cs + a1 * sn) * sc);
}

// ---------------- V transpose + key-permute ----------------
__global__ __launch_bounds__(256) void vtrans_kernel(const u16* __restrict__ kvb,
                                                     u16* __restrict__ vtb) {
  __shared__ __align__(16) u16 lT[64][72];
  const int tid = threadIdx.x;
  const int s0 = blockIdx.x * 64, d0 = blockIdx.y * 64;
  const int b = blockIdx.z >> 2, kh = blockIdx.z & 3;
  const u16* src = kvb + ((size_t)b * 2048) * 1024 + 512 + kh * 128;
#pragma unroll
  for (int i = 0; i < 2; i++) {
    int slot = tid + i * 256;
    int sl = slot >> 3, colv = slot & 7;
    *(us8*)&lT[sl][colv * 8] =
        *(const us8*)(src + (size_t)(s0 + sl) * 1024 + d0 + colv * 8);
  }
  __syncthreads();
  u16* dst = vtb + ((size_t)(b * 4 + kh) * 128) * 2048;
#pragma unroll
  for (int i = 0; i < 2; i++) {
    int slot = tid + i * 256;
    int dd = slot >> 3, colv = slot & 7;
    us8 v;
#pragma unroll
    for (int j = 0; j < 8; j++) {
      int p = colv * 8 + j;
      int g = p & 32, q5 = p & 31, lqp = q5 >> 3, jp = q5 & 7;
      int key = g + ((jp < 4) ? (4 * lqp + jp) : (12 + 4 * lqp + jp));
      v[j] = lT[key][dd];
    }
    *(us8*)(dst + (size_t)(d0 + dd) * 2048 + s0 + colv * 8) = v;
  }
}

// ---------------- Flash attention (R1-exact; plateau accepted) ------------
// R1 VALU-shave null, R2 prefetch -3%, R3/R5 split-K spilled, R6 split-K
// clean but no overlap: total regs (~124 arch + 64 AGPR = 188) cap HW at
// 2 waves/SIMD regardless of grid. ~719 TF effective = the 2-wave serial-
// chain plateau of this structure. Leave as-is.
__global__ __launch_bounds__(256, 2) void attn_kernel(const u16* __restrict__ qb,
                                                      const u16* __restrict__ kvb,
                                                      const u16* __restrict__ vtb,
                                                      u16* __restrict__ ob) {
  __shared__ __align__(16) u16 lK[64][128];   // [key][d], block c at c^(key&15)
  __shared__ __align__(16) u16 lV[128][64];   // [d][key'], block c at c^(d&7)
  __shared__ float lRed[4][4][16];            // [wave][lq][lr] epilogue scratch
  __shared__ float lBc[4][16];                // [wave][row] epilogue broadcast
  const int tid = threadIdx.x;
  const int w = tid >> 6, l = tid & 63, lr = l & 15, lq = l >> 4;
  const int qt = blockIdx.x, hb = blockIdx.y;
  const int b = hb >> 4, h = hb & 15, kh = h >> 2;
  const u16* kptr = kvb + (size_t)b * 2048 * 1024 + kh * 128;
  const u16* vptr = vtb + (size_t)(b * 4 + kh) * 128 * 2048;
  const int qrow0 = qt * 128 + w * 32;

  const int ksrow = l >> 4;                    // K staging: 4 rows x 16 blk
  const int vsrow = l >> 3;                    // V staging: 8 rows x 8 blk
  const int vscol = ((l & 7) ^ vsrow) * 8;

  // Q B-fragments: lane holds roped Q[q=qrow0+16nt+lr][d=32kt+8lq+j]
  bh8 qf[2][4];
#pragma unroll
  for (int nt = 0; nt < 2; nt++) {
    const u16* qrow =
        qb + (((size_t)(b * 2048 + qrow0 + 16 * nt + lr)) * 16 + h) * 128;
#pragma unroll
    for (int kt = 0; kt < 4; kt++) qf[nt][kt] = ld8(qrow + kt * 32 + 8 * lq);
  }

  f4 accO[2][8];   // O[q=16nt+4lq+r][d=16dt+lr]
#pragma unroll
  for (int nt = 0; nt < 2; nt++)
#pragma unroll
    for (int d = 0; d < 8; d++) accO[nt][d] = (f4)0.0f;
  float lsum[2] = {0.0f, 0.0f};

  for (int t0 = 0; t0 < 2048; t0 += 64) {
    __syncthreads();
#pragma unroll
    for (int i = 0; i < 4; i++) {
      {  // K tile
        int r0 = w * 16 + i * 4;
        int grow = r0 + ksrow;
        int gcol = ((l & 15) ^ (grow & 15)) * 8;
        gl_lds16(kptr + (size_t)(t0 + grow) * 1024 + gcol, &lK[r0][0]);
      }
      {  // V^T tile
        int r0 = w * 32 + i * 8;
        int grow = r0 + vsrow;
        gl_lds16(vptr + (size_t)grow * 2048 + t0 + vscol, &lV[r0][0]);
      }
    }
    __syncthreads();

    // S^T = K Q^T (ak reads shared across both nt)
    f4 accS[4][2];
#pragma unroll
    for (int mt = 0; mt < 4; mt++)
#pragma unroll
      for (int nt = 0; nt < 2; nt++) accS[mt][nt] = (f4)0.0f;
#pragma unroll
    for (int kt = 0; kt < 4; kt++) {
      bh8 ak[4];
#pragma unroll
      for (int mt = 0; mt < 4; mt++)
        ak[mt] = ld8(&lK[16 * mt + lr][((4 * kt + lq) ^ lr) * 8]);
      __builtin_amdgcn_s_setprio(1);
#pragma unroll
      for (int mt = 0; mt < 4; mt++)
#pragma unroll
        for (int nt = 0; nt < 2; nt++)
          accS[mt][nt] = MFMA16(ak[mt], qf[nt][kt], accS[mt][nt]);
      __builtin_amdgcn_s_setprio(0);
    }

    // p = exp2(s); packed-RNE convert (v_cvt_pk_bf16_f32); row-sum accum
    u32 pkl[4][2][2];
#pragma unroll
    for (int nt = 0; nt < 2; nt++)
#pragma unroll
      for (int mt = 0; mt < 4; mt++) {
        float p0 = exp2f(accS[mt][nt][0]);
        float p1 = exp2f(accS[mt][nt][1]);
        float p2 = exp2f(accS[mt][nt][2]);
        float p3 = exp2f(accS[mt][nt][3]);
        lsum[nt] += (p0 + p1) + (p2 + p3);
        pkl[mt][nt][0] = cvt_pk_bf16(p0, p1);
        pkl[mt][nt][1] = cvt_pk_bf16(p2, p3);
      }

    // O += P V (A-frag in-lane; bv reads shared across both nt)
#pragma unroll
    for (int kf = 0; kf < 2; kf++) {
      bh8 ap[2];
#pragma unroll
      for (int nt = 0; nt < 2; nt++)
        ap[nt] = __builtin_bit_cast(
            bh8, (uint4){pkl[2 * kf][nt][0], pkl[2 * kf][nt][1],
                         pkl[2 * kf + 1][nt][0], pkl[2 * kf + 1][nt][1]});
#pragma unroll
      for (int d = 0; d < 8; d++) {
        bh8 bv = ld8(&lV[16 * d + lr][((4 * kf + lq) ^ (lr & 7)) * 8]);
        __builtin_amdgcn_s_setprio(1);
#pragma unroll
        for (int nt = 0; nt < 2; nt++)
          accO[nt][d] = MFMA16(ap[nt], bv, accO[nt][d]);
        __builtin_amdgcn_s_setprio(0);
      }
    }
  }

  // epilogue: reduce row sums across lq, O /= l, write [b][s][h][d] bf16
#pragma unroll
  for (int nt = 0; nt < 2; nt++) {
    lRed[w][lq][lr] = lsum[nt];   // same-wave LDS, in-order per wave
    float lt =
        (lRed[w][0][lr] + lRed[w][1][lr]) + (lRed[w][2][lr] + lRed[w][3][lr]);
    float invl = 1.0f / lt;
    if (lq == 0) lBc[w][lr] = invl;
    float ir[4];
#pragma unroll
    for (int r = 0; r < 4; r++) ir[r] = lBc[w][4 * lq + r];
#pragma unroll
    for (int d = 0; d < 8; d++) {
      int dc = 16 * d + lr;
#pragma unroll
      for (int r = 0; r < 4; r++) {
        int srow = qrow0 + 16 * nt + 4 * lq + r;
        ob[(((size_t)(b * 2048 + srow)) * 16 + h) * 128 + dc] =
            f2bf(accO[nt][d][r] * ir[r]);
      }
    }
  }
}

extern "C" void kernel_launch(void* const* d_in, const int* in_sizes, int n_in,
                              void* d_out, int out_size, void* d_ws, size_t ws_size,
                              hipStream_t stream) {
  const float* x   = (const float*)d_in[0];
  const float* Wq  = (const float*)d_in[1];
  const float* bq  = (const float*)d_in[2];
  const float* Wkv = (const float*)d_in[3];
  const float* bkv = (const float*)d_in[4];
  const float* Wo  = (const float*)d_in[5];
  float* out = (float*)d_out;

  u16* xb    = (u16*)d_ws;          // 4096x2048
  u16* wqb   = xb + 8388608;        // 2048x2048  (wkvb contiguous -> fused W)
  u16* wkvb  = wqb + 4194304;       // 1024x2048
  u16* wob   = wkvb + 2097152;      // 2048x2048
  u16* qbf   = wob + 4194304;       // [b][s][16][128] (roped by rope_kernel)
  u16* kvbf  = qbf + 8388608;       // [b][s][1024]
  u16* vtb   = kvbf + 4194304;      // [b][kh][128][2048] (key-permuted)
  u16* attnb = vtb + 2097152;       // [b][s][16][128]

  conv4_kernel<<<18432, 256, 0, stream>>>(x, Wq, Wkv, Wo, xb, wqb, wkvb, wob);
  gemm_qkv<<<dim3(12, 16), 512, 0, stream>>>(xb, wqb, bq, bkv, qbf, kvbf);
  rope_kernel<<<20480, 256, 0, stream>>>(qbf, kvbf);
  vtrans_kernel<<<dim3(32, 2, 8), 256, 0, stream>>>(kvbf, vtb);
  attn_kernel<<<dim3(16, 32), 256, 0, stream>>>(qbf, kvbf, vtb, attnb);
  gemm_bt<<<dim3(8, 16), 512, 0, stream>>>(attnb, wob, out, 4096, 2048, 2048);
}

// Round 10
// 316.393 us; speedup vs baseline: 1.0876x; 1.0876x over previous
//
#include <hip/hip_runtime.h>
#include <math.h>

typedef unsigned short u16;
typedef unsigned int u32;
typedef unsigned short us4 __attribute__((ext_vector_type(4)));
typedef unsigned short us8 __attribute__((ext_vector_type(8)));
typedef short bh8 __attribute__((ext_vector_type(8)));   // 8 bf16 (guide §3)
typedef float f4 __attribute__((ext_vector_type(4)));

#define MFMA16(a, b, c) __builtin_amdgcn_mfma_f32_16x16x32_bf16((a), (b), (c), 0, 0, 0)

__device__ __forceinline__ u16 f2bf(float f) {
  unsigned u = __builtin_bit_cast(unsigned, f);
  u += 0x7FFFu + ((u >> 16) & 1u);   // RNE
  return (u16)(u >> 16);
}
__device__ __forceinline__ float bf2f(u16 h) {
  return __builtin_bit_cast(float, ((unsigned)h) << 16);
}
// gfx950 packed f32->bf16 RNE convert (T12 recipe: no builtin, inline asm)
__device__ __forceinline__ u32 cvt_pk_bf16(float lo, float hi) {
  u32 r;
  asm("v_cvt_pk_bf16_f32 %0, %1, %2" : "=v"(r) : "v"(lo), "v"(hi));
  return r;
}
__device__ __forceinline__ bh8 ld8(const u16* p) {
  return __builtin_bit_cast(bh8, *(const us8*)p);
}
// async global->LDS, 16B per lane. LDS dest = wave-uniform base + lane*16.
__device__ __forceinline__ void gl_lds16(const u16* g, u16* l) {
  __builtin_amdgcn_global_load_lds(
      (const __attribute__((address_space(1))) u32*)g,
      (__attribute__((address_space(3))) u32*)l, 16, 0, 0);
}

// ---------------- fused fp32 -> bf16 (x, Wq, Wkv, Wo) ----------------
__global__ __launch_bounds__(256) void conv4_kernel(const float* __restrict__ x,
                                                    const float* __restrict__ wq,
                                                    const float* __restrict__ wkv,
                                                    const float* __restrict__ wo,
                                                    u16* __restrict__ xb,
                                                    u16* __restrict__ wqb,
                                                    u16* __restrict__ wkvb,
                                                    u16* __restrict__ wob) {
  int i = blockIdx.x * 256 + threadIdx.x;
  const float* in;
  u16* out;
  int j;
  if (i < 2097152) { in = x; out = xb; j = i; }
  else if (i < 3145728) { in = wq; out = wqb; j = i - 2097152; }
  else if (i < 3670016) { in = wkv; out = wkvb; j = i - 3145728; }
  else { in = wo; out = wob; j = i - 3670016; }
  float4 v = ((const float4*)in)[j];
  us4 o;
  o[0] = f2bf(v.x); o[1] = f2bf(v.y); o[2] = f2bf(v.z); o[3] = f2bf(v.w);
  *(us4*)(out + (size_t)j * 4) = o;
}

// ---------------- fused QKV projection, dbuf prefetch K-loop (R15) --------
// R8's 256-sq 8-phase port regressed (grid underfill 192/128 blocks +
// drain-0 vmcnt); this 128-sq dbuf loop is the shape-appropriate optimum.
__global__ __launch_bounds__(256) void gemm_qkv(const u16* __restrict__ A,
                                                const u16* __restrict__ W,
                                                const float* __restrict__ bq,
                                                const float* __restrict__ bkv,
                                                u16* __restrict__ qout,
                                                u16* __restrict__ kvout) {
  const int K = 2048;
  __shared__ __align__(16) u16 lA[2][128][64];
  __shared__ __align__(16) u16 lB[2][128][64];
  const int tid = threadIdx.x;
  const int w = tid >> 6, l = tid & 63, lr = l & 15, lq = l >> 4;
  const int wm = w >> 1, wn = w & 1;
  const int rowBase = blockIdx.y * 128, colBase = blockIdx.x * 128;
  const int srow = l >> 3;
  const int scol = ((l & 7) ^ srow) * 8;

  f4 acc[4][4];
#pragma unroll
  for (int i = 0; i < 4; i++)
#pragma unroll
    for (int j = 0; j < 4; j++) acc[i][j] = (f4)0.0f;

  auto STAGE = [&](int b, int k0) {
#pragma unroll
    for (int i = 0; i < 4; i++) {
      int r0 = w * 32 + i * 8;
      int grow = r0 + srow;
      gl_lds16(A + (size_t)(rowBase + grow) * K + k0 + scol, &lA[b][r0][0]);
      gl_lds16(W + (size_t)(colBase + grow) * K + k0 + scol, &lB[b][r0][0]);
    }
  };

  STAGE(0, 0);
  __syncthreads();
  for (int t = 0; t < 32; t++) {
    if (t + 1 < 32) STAGE((t + 1) & 1, (t + 1) * 64);
    __builtin_amdgcn_sched_barrier(0);   // keep stage issue ahead of ds_reads
    const u16(*pA)[64] = lA[t & 1];
    const u16(*pB)[64] = lB[t & 1];
#pragma unroll
    for (int kk = 0; kk < 64; kk += 32) {
      bh8 af[4], bf[4];
#pragma unroll
      for (int q = 0; q < 4; q++) {
        int c = ((((kk >> 3) + lq) ^ (lr & 7)) * 8);
        af[q] = ld8(&pA[wm * 64 + q * 16 + lr][c]);
        bf[q] = ld8(&pB[wn * 64 + q * 16 + lr][c]);
      }
#pragma unroll
      for (int mt = 0; mt < 4; mt++)
#pragma unroll
        for (int nt = 0; nt < 4; nt++)
          acc[mt][nt] = MFMA16(af[mt], bf[nt], acc[mt][nt]);
    }
    __syncthreads();   // drains vmcnt(0)+lgkmcnt(0): t+1 landed, reads done
  }
#pragma unroll
  for (int mt = 0; mt < 4; mt++) {
#pragma unroll
    for (int nt = 0; nt < 4; nt++) {
      int col = colBase + wn * 64 + nt * 16 + lr;
      float bv = (col < 2048) ? bq[col] : bkv[col - 2048];
#pragma unroll
      for (int r = 0; r < 4; r++) {
        int row = rowBase + wm * 64 + mt * 16 + 4 * lq + r;
        float v = acc[mt][nt][r] + bv;
        if (col < 2048)
          qout[(size_t)row * 2048 + col] = f2bf(v);
        else
          kvout[(size_t)row * 1024 + col - 2048] = f2bf(v);
      }
    }
  }
}

// ---------------- O projection: C = A * W^T (fp32 out), same R15 loop -----
__global__ __launch_bounds__(256) void gemm_bt(const u16* __restrict__ A,
                                               const u16* __restrict__ W,
                                               float* __restrict__ outp,
                                               int M, int N, int K) {
  __shared__ __align__(16) u16 lA[2][128][64];
  __shared__ __align__(16) u16 lB[2][128][64];
  const int tid = threadIdx.x;
  const int w = tid >> 6, l = tid & 63, lr = l & 15, lq = l >> 4;
  const int wm = w >> 1, wn = w & 1;
  const int rowBase = blockIdx.y * 128, colBase = blockIdx.x * 128;
  const int srow = l >> 3;
  const int scol = ((l & 7) ^ srow) * 8;

  f4 acc[4][4];
#pragma unroll
  for (int i = 0; i < 4; i++)
#pragma unroll
    for (int j = 0; j < 4; j++) acc[i][j] = (f4)0.0f;

  auto STAGE = [&](int b, int k0) {
#pragma unroll
    for (int i = 0; i < 4; i++) {
      int r0 = w * 32 + i * 8;
      int grow = r0 + srow;
      gl_lds16(A + (size_t)(rowBase + grow) * K + k0 + scol, &lA[b][r0][0]);
      gl_lds16(W + (size_t)(colBase + grow) * K + k0 + scol, &lB[b][r0][0]);
    }
  };

  const int NT = K >> 6;
  STAGE(0, 0);
  __syncthreads();
  for (int t = 0; t < NT; t++) {
    if (t + 1 < NT) STAGE((t + 1) & 1, (t + 1) * 64);
    __builtin_amdgcn_sched_barrier(0);
    const u16(*pA)[64] = lA[t & 1];
    const u16(*pB)[64] = lB[t & 1];
#pragma unroll
    for (int kk = 0; kk < 64; kk += 32) {
      bh8 af[4], bf[4];
#pragma unroll
      for (int q = 0; q < 4; q++) {
        int c = ((((kk >> 3) + lq) ^ (lr & 7)) * 8);
        af[q] = ld8(&pA[wm * 64 + q * 16 + lr][c]);
        bf[q] = ld8(&pB[wn * 64 + q * 16 + lr][c]);
      }
#pragma unroll
      for (int mt = 0; mt < 4; mt++)
#pragma unroll
        for (int nt = 0; nt < 4; nt++)
          acc[mt][nt] = MFMA16(af[mt], bf[nt], acc[mt][nt]);
    }
    __syncthreads();
  }
#pragma unroll
  for (int mt = 0; mt < 4; mt++) {
#pragma unroll
    for (int nt = 0; nt < 4; nt++) {
      int col = colBase + wn * 64 + nt * 16 + lr;
#pragma unroll
      for (int r = 0; r < 4; r++) {
        int row = rowBase + wm * 64 + mt * 16 + 4 * lq + r;
        outp[(size_t)row * N + col] = acc[mt][nt][r];
      }
    }
  }
}

// -------- merged RoPE (q+k, R5-exact math) + V transpose (R18) ------------
// rope blocks [0,20480): identical element mapping/arithmetic to the R7
// standalone rope_kernel. vtrans blocks [20480,20992): identical to the R7
// vtrans_kernel with flattened block index. Data-disjoint (rope: q + k-half
// of kv; vtrans: v-half of kv -> vtb) -> safe in one dispatch, saves one
// launch + gap. Uniform per-block branch; LDS/__syncthreads only on the
// vtrans path.
__global__ __launch_bounds__(256) void ropevt_kernel(u16* __restrict__ qb,
                                                     u16* __restrict__ kvb,
                                                     u16* __restrict__ vtb) {
  __shared__ __align__(16) u16 lT[64][72];
  const int tid = threadIdx.x;
  if (blockIdx.x < 20480) {
    const int NQ = 2 * 2048 * 16 * 64;
    int idx = blockIdx.x * 256 + tid;
    u16 *p0, *p1;
    int i, s;
    float sc;
    if (idx < NQ) {
      i = idx & 63;
      int h = (idx >> 6) & 15;
      s = (idx >> 10) & 2047;
      int b = idx >> 21;
      size_t base = (((size_t)(b * 2048 + s)) * 16 + h) * 128;
      p0 = qb + base + i;
      p1 = qb + base + 64 + i;
      sc = 0.12751879522655792f;  // 128^-0.5 * log2(e)
    } else {
      int j = idx - NQ;
      i = j & 63;
      int kh = (j >> 6) & 3;
      s = (j >> 8) & 2047;
      int b = j >> 19;
      size_t base = ((size_t)(b * 2048 + s)) * 1024 + kh * 128;
      p0 = kvb + base + i;
      p1 = kvb + base + 64 + i;
      sc = 1.0f;
    }
    float invf = exp2f(-(float)i * 0.20762050593046012f);
    float ang = (float)s * invf;
    float sn, cs;
    sincosf(ang, &sn, &cs);
    float a1 = bf2f(*p0), a2 = bf2f(*p1);
    *p0 = f2bf((a1 * cs - a2 * sn) * sc);
    *p1 = f2bf((a2 * cs + a1 * sn) * sc);
  } else {
    const int z = blockIdx.x - 20480;               // [0,512)
    const int s0 = (z & 31) * 64, d0 = ((z >> 5) & 1) * 64;
    const int zz = z >> 6, b = zz >> 2, kh = zz & 3;
    const u16* src = kvb + ((size_t)b * 2048) * 1024 + 512 + kh * 128;
#pragma unroll
    for (int i = 0; i < 2; i++) {
      int slot = tid + i * 256;
      int sl = slot >> 3, colv = slot & 7;
      *(us8*)&lT[sl][colv * 8] =
          *(const us8*)(src + (size_t)(s0 + sl) * 1024 + d0 + colv * 8);
    }
    __syncthreads();
    u16* dst = vtb + ((size_t)(b * 4 + kh) * 128) * 2048;
#pragma unroll
    for (int i = 0; i < 2; i++) {
      int slot = tid + i * 256;
      int dd = slot >> 3, colv = slot & 7;
      us8 v;
#pragma unroll
      for (int j = 0; j < 8; j++) {
        int p = colv * 8 + j;
        int g = p & 32, q5 = p & 31, lqp = q5 >> 3, jp = q5 & 7;
        int key = g + ((jp < 4) ? (4 * lqp + jp) : (12 + 4 * lqp + jp));
        v[j] = lT[key][dd];
      }
      *(us8*)(dst + (size_t)(d0 + dd) * 2048 + s0 + colv * 8) = v;
    }
  }
}

// ---------------- Flash attention (R1-exact; plateau accepted) ------------
// R1 VALU-shave null, R2 prefetch -3%, R3/R5 split-K spilled, R6 split-K
// clean but no overlap (arch 124 + 64 AGPR = 188 regs -> 2 waves/SIMD cap),
// R9 in-reg q-rope failed numerics (contraction). ~719 TF = this
// structure's 2-wave serial-chain plateau. Frozen.
__global__ __launch_bounds__(256, 2) void attn_kernel(const u16* __restrict__ qb,
                                                      const u16* __restrict__ kvb,
                                                      const u16* __restrict__ vtb,
                                                      u16* __restrict__ ob) {
  __shared__ __align__(16) u16 lK[64][128];   // [key][d], block c at c^(key&15)
  __shared__ __align__(16) u16 lV[128][64];   // [d][key'], block c at c^(d&7)
  __shared__ float lRed[4][4][16];            // [wave][lq][lr] epilogue scratch
  __shared__ float lBc[4][16];                // [wave][row] epilogue broadcast
  const int tid = threadIdx.x;
  const int w = tid >> 6, l = tid & 63, lr = l & 15, lq = l >> 4;
  const int qt = blockIdx.x, hb = blockIdx.y;
  const int b = hb >> 4, h = hb & 15, kh = h >> 2;
  const u16* kptr = kvb + (size_t)b * 2048 * 1024 + kh * 128;
  const u16* vptr = vtb + (size_t)(b * 4 + kh) * 128 * 2048;
  const int qrow0 = qt * 128 + w * 32;

  const int ksrow = l >> 4;                    // K staging: 4 rows x 16 blk
  const int vsrow = l >> 3;                    // V staging: 8 rows x 8 blk
  const int vscol = ((l & 7) ^ vsrow) * 8;

  // Q B-fragments: lane holds roped Q[q=qrow0+16nt+lr][d=32kt+8lq+j]
  bh8 qf[2][4];
#pragma unroll
  for (int nt = 0; nt < 2; nt++) {
    const u16* qrow =
        qb + (((size_t)(b * 2048 + qrow0 + 16 * nt + lr)) * 16 + h) * 128;
#pragma unroll
    for (int kt = 0; kt < 4; kt++) qf[nt][kt] = ld8(qrow + kt * 32 + 8 * lq);
  }

  f4 accO[2][8];   // O[q=16nt+4lq+r][d=16dt+lr]
#pragma unroll
  for (int nt = 0; nt < 2; nt++)
#pragma unroll
    for (int d = 0; d < 8; d++) accO[nt][d] = (f4)0.0f;
  float lsum[2] = {0.0f, 0.0f};

  for (int t0 = 0; t0 < 2048; t0 += 64) {
    __syncthreads();
#pragma unroll
    for (int i = 0; i < 4; i++) {
      {  // K tile
        int r0 = w * 16 + i * 4;
        int grow = r0 + ksrow;
        int gcol = ((l & 15) ^ (grow & 15)) * 8;
        gl_lds16(kptr + (size_t)(t0 + grow) * 1024 + gcol, &lK[r0][0]);
      }
      {  // V^T tile
        int r0 = w * 32 + i * 8;
        int grow = r0 + vsrow;
        gl_lds16(vptr + (size_t)grow * 2048 + t0 + vscol, &lV[r0][0]);
      }
    }
    __syncthreads();

    // S^T = K Q^T (ak reads shared across both nt)
    f4 accS[4][2];
#pragma unroll
    for (int mt = 0; mt < 4; mt++)
#pragma unroll
      for (int nt = 0; nt < 2; nt++) accS[mt][nt] = (f4)0.0f;
#pragma unroll
    for (int kt = 0; kt < 4; kt++) {
      bh8 ak[4];
#pragma unroll
      for (int mt = 0; mt < 4; mt++)
        ak[mt] = ld8(&lK[16 * mt + lr][((4 * kt + lq) ^ lr) * 8]);
      __builtin_amdgcn_s_setprio(1);
#pragma unroll
      for (int mt = 0; mt < 4; mt++)
#pragma unroll
        for (int nt = 0; nt < 2; nt++)
          accS[mt][nt] = MFMA16(ak[mt], qf[nt][kt], accS[mt][nt]);
      __builtin_amdgcn_s_setprio(0);
    }

    // p = exp2(s); packed-RNE convert (v_cvt_pk_bf16_f32); row-sum accum
    u32 pkl[4][2][2];
#pragma unroll
    for (int nt = 0; nt < 2; nt++)
#pragma unroll
      for (int mt = 0; mt < 4; mt++) {
        float p0 = exp2f(accS[mt][nt][0]);
        float p1 = exp2f(accS[mt][nt][1]);
        float p2 = exp2f(accS[mt][nt][2]);
        float p3 = exp2f(accS[mt][nt][3]);
        lsum[nt] += (p0 + p1) + (p2 + p3);
        pkl[mt][nt][0] = cvt_pk_bf16(p0, p1);
        pkl[mt][nt][1] = cvt_pk_bf16(p2, p3);
      }

    // O += P V (A-frag in-lane; bv reads shared across both nt)
#pragma unroll
    for (int kf = 0; kf < 2; kf++) {
      bh8 ap[2];
#pragma unroll
      for (int nt = 0; nt < 2; nt++)
        ap[nt] = __builtin_bit_cast(
            bh8, (uint4){pkl[2 * kf][nt][0], pkl[2 * kf][nt][1],
                         pkl[2 * kf + 1][nt][0], pkl[2 * kf + 1][nt][1]});
#pragma unroll
      for (int d = 0; d < 8; d++) {
        bh8 bv = ld8(&lV[16 * d + lr][((4 * kf + lq) ^ (lr & 7)) * 8]);
        __builtin_amdgcn_s_setprio(1);
#pragma unroll
        for (int nt = 0; nt < 2; nt++)
          accO[nt][d] = MFMA16(ap[nt], bv, accO[nt][d]);
        __builtin_amdgcn_s_setprio(0);
      }
    }
  }

  // epilogue: reduce row sums across lq, O /= l, write [b][s][h][d] bf16
#pragma unroll
  for (int nt = 0; nt < 2; nt++) {
    lRed[w][lq][lr] = lsum[nt];   // same-wave LDS, in-order per wave
    float lt =
        (lRed[w][0][lr] + lRed[w][1][lr]) + (lRed[w][2][lr] + lRed[w][3][lr]);
    float invl = 1.0f / lt;
    if (lq == 0) lBc[w][lr] = invl;
    float ir[4];
#pragma unroll
    for (int r = 0; r < 4; r++) ir[r] = lBc[w][4 * lq + r];
#pragma unroll
    for (int d = 0; d < 8; d++) {
      int dc = 16 * d + lr;
#pragma unroll
      for (int r = 0; r < 4; r++) {
        int srow = qrow0 + 16 * nt + 4 * lq + r;
        ob[(((size_t)(b * 2048 + srow)) * 16 + h) * 128 + dc] =
            f2bf(accO[nt][d][r] * ir[r]);
      }
    }
  }
}

extern "C" void kernel_launch(void* const* d_in, const int* in_sizes, int n_in,
                              void* d_out, int out_size, void* d_ws, size_t ws_size,
                              hipStream_t stream) {
  const float* x   = (const float*)d_in[0];
  const float* Wq  = (const float*)d_in[1];
  const float* bq  = (const float*)d_in[2];
  const float* Wkv = (const float*)d_in[3];
  const float* bkv = (const float*)d_in[4];
  const float* Wo  = (const float*)d_in[5];
  float* out = (float*)d_out;

  u16* xb    = (u16*)d_ws;          // 4096x2048
  u16* wqb   = xb + 8388608;        // 2048x2048  (wkvb contiguous -> fused W)
  u16* wkvb  = wqb + 4194304;       // 1024x2048
  u16* wob   = wkvb + 2097152;      // 2048x2048
  u16* qbf   = wob + 4194304;       // [b][s][16][128] (roped by ropevt)
  u16* kvbf  = qbf + 8388608;       // [b][s][1024]   (k roped by ropevt)
  u16* vtb   = kvbf + 4194304;      // [b][kh][128][2048] (key-permuted)
  u16* attnb = vtb + 2097152;       // [b][s][16][128]

  conv4_kernel<<<18432, 256, 0, stream>>>(x, Wq, Wkv, Wo, xb, wqb, wkvb, wob);
  gemm_qkv<<<dim3(24, 32), 256, 0, stream>>>(xb, wqb, bq, bkv, qbf, kvbf);
  ropevt_kernel<<<20992, 256, 0, stream>>>(qbf, kvbf, vtb);
  attn_kernel<<<dim3(16, 32), 256, 0, stream>>>(qbf, kvbf, vtb, attnb);
  gemm_bt<<<dim3(16, 32), 256, 0, stream>>>(attnb, wob, out, 4096, 2048, 2048);
}

// Round 13
// 313.964 us; speedup vs baseline: 1.0960x; 1.0077x over previous
//
#include <hip/hip_runtime.h>
#include <math.h>

typedef unsigned short u16;
typedef unsigned int u32;
typedef unsigned short us4 __attribute__((ext_vector_type(4)));
typedef unsigned short us8 __attribute__((ext_vector_type(8)));
typedef short bh8 __attribute__((ext_vector_type(8)));   // 8 bf16 (guide §3)
typedef float f4 __attribute__((ext_vector_type(4)));

#define MFMA16(a, b, c) __builtin_amdgcn_mfma_f32_16x16x32_bf16((a), (b), (c), 0, 0, 0)

__device__ __forceinline__ u16 f2bf(float f) {
  unsigned u = __builtin_bit_cast(unsigned, f);
  u += 0x7FFFu + ((u >> 16) & 1u);   // RNE
  return (u16)(u >> 16);
}
__device__ __forceinline__ float bf2f(u16 h) {
  return __builtin_bit_cast(float, ((unsigned)h) << 16);
}
// gfx950 packed f32->bf16 RNE convert (T12 recipe: no builtin, inline asm)
__device__ __forceinline__ u32 cvt_pk_bf16(float lo, float hi) {
  u32 r;
  asm("v_cvt_pk_bf16_f32 %0, %1, %2" : "=v"(r) : "v"(lo), "v"(hi));
  return r;
}
__device__ __forceinline__ bh8 ld8(const u16* p) {
  return __builtin_bit_cast(bh8, *(const us8*)p);
}
// async global->LDS, 16B per lane. LDS dest = wave-uniform base + lane*16.
__device__ __forceinline__ void gl_lds16(const u16* g, u16* l) {
  __builtin_amdgcn_global_load_lds(
      (const __attribute__((address_space(1))) u32*)g,
      (__attribute__((address_space(3))) u32*)l, 16, 0, 0);
}

// ---------------- fused fp32 -> bf16 (x, Wq, Wkv, Wo) ----------------
__global__ __launch_bounds__(256) void conv4_kernel(const float* __restrict__ x,
                                                    const float* __restrict__ wq,
                                                    const float* __restrict__ wkv,
                                                    const float* __restrict__ wo,
                                                    u16* __restrict__ xb,
                                                    u16* __restrict__ wqb,
                                                    u16* __restrict__ wkvb,
                                                    u16* __restrict__ wob) {
  int i = blockIdx.x * 256 + threadIdx.x;
  const float* in;
  u16* out;
  int j;
  if (i < 2097152) { in = x; out = xb; j = i; }
  else if (i < 3145728) { in = wq; out = wqb; j = i - 2097152; }
  else if (i < 3670016) { in = wkv; out = wkvb; j = i - 3145728; }
  else { in = wo; out = wob; j = i - 3670016; }
  float4 v = ((const float4*)in)[j];
  us4 o;
  o[0] = f2bf(v.x); o[1] = f2bf(v.y); o[2] = f2bf(v.z); o[3] = f2bf(v.w);
  *(us4*)(out + (size_t)j * 4) = o;
}

// ---------------- fused QKV projection, dbuf prefetch K-loop (R15) --------
// R10-exact known-good. R11's barrier-free variant raced (unbounded wave
// drift on duplicated staging halves); this 1-barrier dbuf loop stays.
__global__ __launch_bounds__(256) void gemm_qkv(const u16* __restrict__ A,
                                                const u16* __restrict__ W,
                                                const float* __restrict__ bq,
                                                const float* __restrict__ bkv,
                                                u16* __restrict__ qout,
                                                u16* __restrict__ kvout) {
  const int K = 2048;
  __shared__ __align__(16) u16 lA[2][128][64];
  __shared__ __align__(16) u16 lB[2][128][64];
  const int tid = threadIdx.x;
  const int w = tid >> 6, l = tid & 63, lr = l & 15, lq = l >> 4;
  const int wm = w >> 1, wn = w & 1;
  const int rowBase = blockIdx.y * 128, colBase = blockIdx.x * 128;
  const int srow = l >> 3;
  const int scol = ((l & 7) ^ srow) * 8;

  f4 acc[4][4];
#pragma unroll
  for (int i = 0; i < 4; i++)
#pragma unroll
    for (int j = 0; j < 4; j++) acc[i][j] = (f4)0.0f;

  auto STAGE = [&](int b, int k0) {
#pragma unroll
    for (int i = 0; i < 4; i++) {
      int r0 = w * 32 + i * 8;
      int grow = r0 + srow;
      gl_lds16(A + (size_t)(rowBase + grow) * K + k0 + scol, &lA[b][r0][0]);
      gl_lds16(W + (size_t)(colBase + grow) * K + k0 + scol, &lB[b][r0][0]);
    }
  };

  STAGE(0, 0);
  __syncthreads();
  for (int t = 0; t < 32; t++) {
    if (t + 1 < 32) STAGE((t + 1) & 1, (t + 1) * 64);
    __builtin_amdgcn_sched_barrier(0);   // keep stage issue ahead of ds_reads
    const u16(*pA)[64] = lA[t & 1];
    const u16(*pB)[64] = lB[t & 1];
#pragma unroll
    for (int kk = 0; kk < 64; kk += 32) {
      bh8 af[4], bf[4];
#pragma unroll
      for (int q = 0; q < 4; q++) {
        int c = ((((kk >> 3) + lq) ^ (lr & 7)) * 8);
        af[q] = ld8(&pA[wm * 64 + q * 16 + lr][c]);
        bf[q] = ld8(&pB[wn * 64 + q * 16 + lr][c]);
      }
#pragma unroll
      for (int mt = 0; mt < 4; mt++)
#pragma unroll
        for (int nt = 0; nt < 4; nt++)
          acc[mt][nt] = MFMA16(af[mt], bf[nt], acc[mt][nt]);
    }
    __syncthreads();   // drains vmcnt(0)+lgkmcnt(0): t+1 landed, reads done
  }
#pragma unroll
  for (int mt = 0; mt < 4; mt++) {
#pragma unroll
    for (int nt = 0; nt < 4; nt++) {
      int col = colBase + wn * 64 + nt * 16 + lr;
      float bv = (col < 2048) ? bq[col] : bkv[col - 2048];
#pragma unroll
      for (int r = 0; r < 4; r++) {
        int row = rowBase + wm * 64 + mt * 16 + 4 * lq + r;
        float v = acc[mt][nt][r] + bv;
        if (col < 2048)
          qout[(size_t)row * 2048 + col] = f2bf(v);
        else
          kvout[(size_t)row * 1024 + col - 2048] = f2bf(v);
      }
    }
  }
}

// ---------------- O projection: C = A * W^T (fp32 out), same R15 loop -----
__global__ __launch_bounds__(256) void gemm_bt(const u16* __restrict__ A,
                                               const u16* __restrict__ W,
                                               float* __restrict__ outp,
                                               int M, int N, int K) {
  __shared__ __align__(16) u16 lA[2][128][64];
  __shared__ __align__(16) u16 lB[2][128][64];
  const int tid = threadIdx.x;
  const int w = tid >> 6, l = tid & 63, lr = l & 15, lq = l >> 4;
  const int wm = w >> 1, wn = w & 1;
  const int rowBase = blockIdx.y * 128, colBase = blockIdx.x * 128;
  const int srow = l >> 3;
  const int scol = ((l & 7) ^ srow) * 8;

  f4 acc[4][4];
#pragma unroll
  for (int i = 0; i < 4; i++)
#pragma unroll
    for (int j = 0; j < 4; j++) acc[i][j] = (f4)0.0f;

  auto STAGE = [&](int b, int k0) {
#pragma unroll
    for (int i = 0; i < 4; i++) {
      int r0 = w * 32 + i * 8;
      int grow = r0 + srow;
      gl_lds16(A + (size_t)(rowBase + grow) * K + k0 + scol, &lA[b][r0][0]);
      gl_lds16(W + (size_t)(colBase + grow) * K + k0 + scol, &lB[b][r0][0]);
    }
  };

  const int NT = K >> 6;
  STAGE(0, 0);
  __syncthreads();
  for (int t = 0; t < NT; t++) {
    if (t + 1 < NT) STAGE((t + 1) & 1, (t + 1) * 64);
    __builtin_amdgcn_sched_barrier(0);
    const u16(*pA)[64] = lA[t & 1];
    const u16(*pB)[64] = lB[t & 1];
#pragma unroll
    for (int kk = 0; kk < 64; kk += 32) {
      bh8 af[4], bf[4];
#pragma unroll
      for (int q = 0; q < 4; q++) {
        int c = ((((kk >> 3) + lq) ^ (lr & 7)) * 8);
        af[q] = ld8(&pA[wm * 64 + q * 16 + lr][c]);
        bf[q] = ld8(&pB[wn * 64 + q * 16 + lr][c]);
      }
#pragma unroll
      for (int mt = 0; mt < 4; mt++)
#pragma unroll
        for (int nt = 0; nt < 4; nt++)
          acc[mt][nt] = MFMA16(af[mt], bf[nt], acc[mt][nt]);
    }
    __syncthreads();
  }
#pragma unroll
  for (int mt = 0; mt < 4; mt++) {
#pragma unroll
    for (int nt = 0; nt < 4; nt++) {
      int col = colBase + wn * 64 + nt * 16 + lr;
#pragma unroll
      for (int r = 0; r < 4; r++) {
        int row = rowBase + wm * 64 + mt * 16 + 4 * lq + r;
        outp[(size_t)row * N + col] = acc[mt][nt][r];
      }
    }
  }
}

// -------- merged RoPE (vectorized us8 IO, R20) + V transpose --------------
// R20: rope loads/stores were scalar u16 (2B/lane — Common-mistake #2).
// Each thread now handles 8 consecutive i of one (b,s,[k]h) row: us8 load
// of [i0,i0+8) and partner [64+i0,..). Per-element arithmetic (exp2f,
// sincosf, f2bf, same mul order) is UNCHANGED -> bitwise-identical output.
// Blocks: [0,2048) q-rope, [2048,2560) k-rope, [2560,3072) vtrans.
__global__ __launch_bounds__(256) void ropevt_kernel(u16* __restrict__ qb,
                                                     u16* __restrict__ kvb,
                                                     u16* __restrict__ vtb) {
  __shared__ __align__(16) u16 lT[64][72];
  const int tid = threadIdx.x;
  const int bid = blockIdx.x;
  if (bid < 2560) {
    u16 *p0;
    int i0, s;
    float sc;
    if (bid < 2048) {                       // q-rope: 524288 threads
      int t = bid * 256 + tid;
      i0 = 8 * (t & 7);
      int h = (t >> 3) & 15;
      s = (t >> 7) & 2047;
      int b = t >> 18;
      p0 = qb + (((size_t)(b * 2048 + s)) * 16 + h) * 128 + i0;
      sc = 0.12751879522655792f;            // 128^-0.5 * log2(e)
    } else {                                // k-rope: 131072 threads
      int t = (bid - 2048) * 256 + tid;
      i0 = 8 * (t & 7);
      int kh = (t >> 3) & 3;
      s = (t >> 5) & 2047;
      int b = t >> 16;
      p0 = kvb + ((size_t)(b * 2048 + s)) * 1024 + kh * 128 + i0;
      sc = 1.0f;
    }
    u16* p1 = p0 + 64;
    us8 v0 = *(const us8*)p0;
    us8 v1 = *(const us8*)p1;
    us8 o0, o1;
#pragma unroll
    for (int j = 0; j < 8; j++) {
      int i = i0 + j;
      float invf = exp2f(-(float)i * 0.20762050593046012f);
      float ang = (float)s * invf;
      float sn, cs;
      sincosf(ang, &sn, &cs);
      float a1 = bf2f(v0[j]), a2 = bf2f(v1[j]);
      o0[j] = f2bf((a1 * cs - a2 * sn) * sc);
      o1[j] = f2bf((a2 * cs + a1 * sn) * sc);
    }
    *(us8*)p0 = o0;
    *(us8*)p1 = o1;
  } else {
    const int z = bid - 2560;                       // [0,512)
    const int s0 = (z & 31) * 64, d0 = ((z >> 5) & 1) * 64;
    const int zz = z >> 6, b = zz >> 2, kh = zz & 3;
    const u16* src = kvb + ((size_t)b * 2048) * 1024 + 512 + kh * 128;
#pragma unroll
    for (int i = 0; i < 2; i++) {
      int slot = tid + i * 256;
      int sl = slot >> 3, colv = slot & 7;
      *(us8*)&lT[sl][colv * 8] =
          *(const us8*)(src + (size_t)(s0 + sl) * 1024 + d0 + colv * 8);
    }
    __syncthreads();
    u16* dst = vtb + ((size_t)(b * 4 + kh) * 128) * 2048;
#pragma unroll
    for (int i = 0; i < 2; i++) {
      int slot = tid + i * 256;
      int dd = slot >> 3, colv = slot & 7;
      us8 v;
#pragma unroll
      for (int j = 0; j < 8; j++) {
        int p = colv * 8 + j;
        int g = p & 32, q5 = p & 31, lqp = q5 >> 3, jp = q5 & 7;
        int key = g + ((jp < 4) ? (4 * lqp + jp) : (12 + 4 * lqp + jp));
        v[j] = lT[key][dd];
      }
      *(us8*)(dst + (size_t)(d0 + dd) * 2048 + s0 + colv * 8) = v;
    }
  }
}

// ---------------- Flash attention (R1-exact; plateau accepted) ------------
__global__ __launch_bounds__(256, 2) void attn_kernel(const u16* __restrict__ qb,
                                                      const u16* __restrict__ kvb,
                                                      const u16* __restrict__ vtb,
                                                      u16* __restrict__ ob) {
  __shared__ __align__(16) u16 lK[64][128];   // [key][d], block c at c^(key&15)
  __shared__ __align__(16) u16 lV[128][64];   // [d][key'], block c at c^(d&7)
  __shared__ float lRed[4][4][16];            // [wave][lq][lr] epilogue scratch
  __shared__ float lBc[4][16];                // [wave][row] epilogue broadcast
  const int tid = threadIdx.x;
  const int w = tid >> 6, l = tid & 63, lr = l & 15, lq = l >> 4;
  const int qt = blockIdx.x, hb = blockIdx.y;
  const int b = hb >> 4, h = hb & 15, kh = h >> 2;
  const u16* kptr = kvb + (size_t)b * 2048 * 1024 + kh * 128;
  const u16* vptr = vtb + (size_t)(b * 4 + kh) * 128 * 2048;
  const int qrow0 = qt * 128 + w * 32;

  const int ksrow = l >> 4;                    // K staging: 4 rows x 16 blk
  const int vsrow = l >> 3;                    // V staging: 8 rows x 8 blk
  const int vscol = ((l & 7) ^ vsrow) * 8;

  // Q B-fragments: lane holds roped Q[q=qrow0+16nt+lr][d=32kt+8lq+j]
  bh8 qf[2][4];
#pragma unroll
  for (int nt = 0; nt < 2; nt++) {
    const u16* qrow =
        qb + (((size_t)(b * 2048 + qrow0 + 16 * nt + lr)) * 16 + h) * 128;
#pragma unroll
    for (int kt = 0; kt < 4; kt++) qf[nt][kt] = ld8(qrow + kt * 32 + 8 * lq);
  }

  f4 accO[2][8];   // O[q=16nt+4lq+r][d=16dt+lr]
#pragma unroll
  for (int nt = 0; nt < 2; nt++)
#pragma unroll
    for (int d = 0; d < 8; d++) accO[nt][d] = (f4)0.0f;
  float lsum[2] = {0.0f, 0.0f};

  for (int t0 = 0; t0 < 2048; t0 += 64) {
    __syncthreads();
#pragma unroll
    for (int i = 0; i < 4; i++) {
      {  // K tile
        int r0 = w * 16 + i * 4;
        int grow = r0 + ksrow;
        int gcol = ((l & 15) ^ (grow & 15)) * 8;
        gl_lds16(kptr + (size_t)(t0 + grow) * 1024 + gcol, &lK[r0][0]);
      }
      {  // V^T tile
        int r0 = w * 32 + i * 8;
        int grow = r0 + vsrow;
        gl_lds16(vptr + (size_t)grow * 2048 + t0 + vscol, &lV[r0][0]);
      }
    }
    __syncthreads();

    // S^T = K Q^T (ak reads shared across both nt)
    f4 accS[4][2];
#pragma unroll
    for (int mt = 0; mt < 4; mt++)
#pragma unroll
      for (int nt = 0; nt < 2; nt++) accS[mt][nt] = (f4)0.0f;
#pragma unroll
    for (int kt = 0; kt < 4; kt++) {
      bh8 ak[4];
#pragma unroll
      for (int mt = 0; mt < 4; mt++)
        ak[mt] = ld8(&lK[16 * mt + lr][((4 * kt + lq) ^ lr) * 8]);
      __builtin_amdgcn_s_setprio(1);
#pragma unroll
      for (int mt = 0; mt < 4; mt++)
#pragma unroll
        for (int nt = 0; nt < 2; nt++)
          accS[mt][nt] = MFMA16(ak[mt], qf[nt][kt], accS[mt][nt]);
      __builtin_amdgcn_s_setprio(0);
    }

    // p = exp2(s); packed-RNE convert (v_cvt_pk_bf16_f32); row-sum accum
    u32 pkl[4][2][2];
#pragma unroll
    for (int nt = 0; nt < 2; nt++)
#pragma unroll
      for (int mt = 0; mt < 4; mt++) {
        float p0 = exp2f(accS[mt][nt][0]);
        float p1 = exp2f(accS[mt][nt][1]);
        float p2 = exp2f(accS[mt][nt][2]);
        float p3 = exp2f(accS[mt][nt][3]);
        lsum[nt] += (p0 + p1) + (p2 + p3);
        pkl[mt][nt][0] = cvt_pk_bf16(p0, p1);
        pkl[mt][nt][1] = cvt_pk_bf16(p2, p3);
      }

    // O += P V (A-frag in-lane; bv reads shared across both nt)
#pragma unroll
    for (int kf = 0; kf < 2; kf++) {
      bh8 ap[2];
#pragma unroll
      for (int nt = 0; nt < 2; nt++)
        ap[nt] = __builtin_bit_cast(
            bh8, (uint4){pkl[2 * kf][nt][0], pkl[2 * kf][nt][1],
                         pkl[2 * kf + 1][nt][0], pkl[2 * kf + 1][nt][1]});
#pragma unroll
      for (int d = 0; d < 8; d++) {
        bh8 bv = ld8(&lV[16 * d + lr][((4 * kf + lq) ^ (lr & 7)) * 8]);
        __builtin_amdgcn_s_setprio(1);
#pragma unroll
        for (int nt = 0; nt < 2; nt++)
          accO[nt][d] = MFMA16(ap[nt], bv, accO[nt][d]);
        __builtin_amdgcn_s_setprio(0);
      }
    }
  }

  // epilogue: reduce row sums across lq, O /= l, write [b][s][h][d] bf16
#pragma unroll
  for (int nt = 0; nt < 2; nt++) {
    lRed[w][lq][lr] = lsum[nt];   // same-wave LDS, in-order per wave
    float lt =
        (lRed[w][0][lr] + lRed[w][1][lr]) + (lRed[w][2][lr] + lRed[w][3][lr]);
    float invl = 1.0f / lt;
    if (lq == 0) lBc[w][lr] = invl;
    float ir[4];
#pragma unroll
    for (int r = 0; r < 4; r++) ir[r] = lBc[w][4 * lq + r];
#pragma unroll
    for (int d = 0; d < 8; d++) {
      int dc = 16 * d + lr;
#pragma unroll
      for (int r = 0; r < 4; r++) {
        int srow = qrow0 + 16 * nt + 4 * lq + r;
        ob[(((size_t)(b * 2048 + srow)) * 16 + h) * 128 + dc] =
            f2bf(accO[nt][d][r] * ir[r]);
      }
    }
  }
}

extern "C" void kernel_launch(void* const* d_in, const int* in_sizes, int n_in,
                              void* d_out, int out_size, void* d_ws, size_t ws_size,
                              hipStream_t stream) {
  const float* x   = (const float*)d_in[0];
  const float* Wq  = (const float*)d_in[1];
  const float* bq  = (const float*)d_in[2];
  const float* Wkv = (const float*)d_in[3];
  const float* bkv = (const float*)d_in[4];
  const float* Wo  = (const float*)d_in[5];
  float* out = (float*)d_out;

  u16* xb    = (u16*)d_ws;          // 4096x2048
  u16* wqb   = xb + 8388608;        // 2048x2048  (wkvb contiguous -> fused W)
  u16* wkvb  = wqb + 4194304;       // 1024x2048
  u16* wob   = wkvb + 2097152;      // 2048x2048
  u16* qbf   = wob + 4194304;       // [b][s][16][128] (roped by ropevt)
  u16* kvbf  = qbf + 8388608;       // [b][s][1024]   (k roped by ropevt)
  u16* vtb   = kvbf + 4194304;      // [b][kh][128][2048] (key-permuted)
  u16* attnb = vtb + 2097152;       // [b][s][16][128]

  conv4_kernel<<<18432, 256, 0, stream>>>(x, Wq, Wkv, Wo, xb, wqb, wkvb, wob);
  gemm_qkv<<<dim3(24, 32), 256, 0, stream>>>(xb, wqb, bq, bkv, qbf, kvbf);
  ropevt_kernel<<<3072, 256, 0, stream>>>(qbf, kvbf, vtb);
  attn_kernel<<<dim3(16, 32), 256, 0, stream>>>(qbf, kvbf, vtb, attnb);
  gemm_bt<<<dim3(16, 32), 256, 0, stream>>>(attnb, wob, out, 4096, 2048, 2048);
}